// Round 1
// baseline (443.982 us; speedup 1.0000x reference)
//
#include <hip/hip_runtime.h>
#include <stdint.h>
#include <stddef.h>

// Problem constants
#define N_ROWS 131072
#define D_DIM  64
#define K_PROT 512
#define ND     (N_ROWS * D_DIM)                       // 8388608 elements per xn copy
#define PO     ((size_t)2 * (size_t)ND)               // proto_out offset (elements)
#define SO     (PO + (size_t)N_ROWS * (size_t)K_PROT) // scalars offset (elements)

typedef float          float4v  __attribute__((ext_vector_type(4)));
typedef short          short8v  __attribute__((ext_vector_type(8)));
typedef unsigned short ushort4v __attribute__((ext_vector_type(4)));

// fp32 -> bf16 RNE (internal MFMA dtype only; d_out itself is fp32)
__device__ __forceinline__ unsigned short f2bf(float f) {
    unsigned int u = __builtin_bit_cast(unsigned int, f);
    return (unsigned short)((u + 0x7FFFu + ((u >> 16) & 1u)) >> 16);
}

// ---------------- prep: re-init workspace accumulators (runs every launch) ----
__global__ void prep_kernel(unsigned int* __restrict__ colmin,
                            float* __restrict__ rowsum) {
    int k = threadIdx.x;          // 512 threads
    colmin[k] = 0x7F800000u;      // +inf bits
    if (k == 0) *rowsum = 0.0f;
}

// ---------------- main fused kernel ------------------------------------------
// grid 2048 x 256 threads. Block handles 64 rows (4 waves x 16 rows).
// LDS = 78084 B  -> 2 blocks/CU (was 86.5 KB -> 1 block/CU).
struct SMem {
    alignas(16) unsigned short wlds[K_PROT * D_DIM]; // 65536 B, swizzled bf16 W
    alignas(16) float w2[K_PROT];                    // 2048 B  (||W_k||^2 fp32)
    alignas(16) float xn2[4][16];                    // 256 B   per-wave row ||xn||^2
    alignas(16) unsigned int colmin[K_PROT];         // 2048 B  block col-min (sq bits)
    alignas(16) unsigned short atile[4][16 * D_DIM]; // 8192 B per-wave swizzled xn tile
    float rowsum;                                    // block sum of sqrt(rowmin)
};

__launch_bounds__(256, 2)
__global__ void main_kernel(const float* __restrict__ x,
                            const float* __restrict__ Wg,
                            unsigned int* __restrict__ colming,
                            float* __restrict__ rowsumg,
                            float* __restrict__ out) {
    __shared__ SMem s;
    const int tid  = threadIdx.x;
    const int wave = tid >> 6;
    const int L    = tid & 63;
    const int q    = L >> 4;   // 16-lane group (quad) 0..3
    const int l4   = L & 15;   // lane within group

    // ---- phase 0: init block LDS accumulators (ordered by phase-1 barrier) ----
    s.colmin[tid]       = 0x7F800000u;
    s.colmin[tid + 256] = 0x7F800000u;
    if (tid == 0) s.rowsum = 0.0f;

    // ---- phase 1a: stage W -> LDS bf16, swizzled; w2 via 16-lane shuffle ----
    // W is 512x64 fp32 = 8192 float4. Chunk = 8 consecutive d (16 B bf16);
    // chunk c of row r stored at c' = c ^ (r&7) => B-frag b128 reads conflict-free.
    // For fixed i, 16 consecutive (16-aligned) tids hold one full W row, so the
    // row norm reduces with 4 shfl_xor — no LDS atomics, no w2 zero-init.
    {
        const float4v* Wv = (const float4v*)Wg;
        #pragma unroll 8
        for (int i = 0; i < 32; ++i) {
            int idx = tid + 256 * i;        // 0..8191
            float4v v = Wv[idx];
            int r    = idx >> 4;            // row 0..511
            int c    = (idx & 15) >> 1;     // chunk 0..7
            int half = idx & 1;             // low/high 8 B of the chunk
            int cp   = c ^ (r & 7);
            ushort4v p = { f2bf(v.x), f2bf(v.y), f2bf(v.z), f2bf(v.w) };
            *(ushort4v*)&s.wlds[r * 64 + cp * 8 + half * 4] = p;
            float ss = v.x * v.x + v.y * v.y + v.z * v.z + v.w * v.w;
            ss += __shfl_xor(ss, 1);
            ss += __shfl_xor(ss, 2);
            ss += __shfl_xor(ss, 4);
            ss += __shfl_xor(ss, 8);
            if ((idx & 15) == 0) s.w2[r] = ss;   // one writer per row
        }
    }

    // ---- phase 1b: load x tile, normalize, emit xn (fp32), build bf16 A-tile ----
    const int rowBase = (int)blockIdx.x * 64 + wave * 16;
    const float4v* xv = (const float4v*)(x + (size_t)rowBase * D_DIM);
    unsigned short* atile = s.atile[wave];

    #pragma unroll
    for (int j = 0; j < 4; ++j) {
        float4v v = xv[j * 64 + L];         // row j*4+q, elems l4*4..+3, coalesced 1 KB
        float ss = v.x * v.x + v.y * v.y + v.z * v.z + v.w * v.w;
        ss += __shfl_xor(ss, 1);
        ss += __shfl_xor(ss, 2);
        ss += __shfl_xor(ss, 4);
        ss += __shfl_xor(ss, 8);            // all 16 lanes of the group share row sum
        float nrm   = sqrtf(ss);
        float scale = 1.0f / fmaxf(nrm, 1e-12f);
        float4v xn  = v * scale;
        int row_l = j * 4 + q;
        int rowg  = rowBase + row_l;
        // fp32 outputs 0 and 1
        *(float4v*)&out[(size_t)rowg * D_DIM + l4 * 4]              = xn;
        *(float4v*)&out[(size_t)ND + (size_t)rowg * D_DIM + l4 * 4] = xn;
        // bf16 A-tile (swizzled like W): chunk c = l4>>1, half = l4&1
        ushort4v p = { f2bf(xn.x), f2bf(xn.y), f2bf(xn.z), f2bf(xn.w) };
        int cp = (l4 >> 1) ^ (row_l & 7);
        *(ushort4v*)&atile[row_l * 64 + cp * 8 + (l4 & 1) * 4] = p;
        if (l4 == 0) s.xn2[wave][row_l] = ss * scale * scale;
    }
    __syncthreads();   // W/w2 visible to all; A-tile/xn2 ordered

    // ---- phase 2: MFMA over 32 col-tiles, distance-1 pipelined + fused epilogue ----
    // A frag: A[m=l4][k=q*8+j (+32*kh)]  -> row l4, chunk kh*4+q of A-tile
    short8v afrag[2];
    #pragma unroll
    for (int kh = 0; kh < 2; ++kh) {
        int cp = (kh * 4 + q) ^ (l4 & 7);
        afrag[kh] = *(const short8v*)&atile[l4 * 64 + cp * 8];
    }
    float4v x2v = *(const float4v*)&s.xn2[wave][q * 4];  // rows q*4..q*4+3

    float rowmin[4] = { __builtin_inff(), __builtin_inff(),
                        __builtin_inff(), __builtin_inff() };
    float* outp = out + PO;

    const int cpb0 = (0 * 4 + q) ^ (l4 & 7);   // B-frag swizzled chunk, kh=0
    const int cpb1 = (1 * 4 + q) ^ (l4 & 7);   // kh=1  (rw&7 == l4&7 since 16|ct*16)

    // prologue: prefetch ct=0
    short8v b0 = *(const short8v*)&s.wlds[l4 * 64 + cpb0 * 8];
    short8v b1 = *(const short8v*)&s.wlds[l4 * 64 + cpb1 * 8];
    float  w2c = s.w2[l4];

    for (int ct = 0; ct < 32; ++ct) {
        // prefetch ct+1 (wraps harmlessly at ct=31) — hides ds_read latency
        int nrw = (((ct + 1) & 31) * 16) + l4;
        short8v nb0 = *(const short8v*)&s.wlds[nrw * 64 + cpb0 * 8];
        short8v nb1 = *(const short8v*)&s.wlds[nrw * 64 + cpb1 * 8];
        float  w2n  = s.w2[nrw];

        float4v acc = { 0.f, 0.f, 0.f, 0.f };
        acc = __builtin_amdgcn_mfma_f32_16x16x32_bf16(afrag[0], b0, acc, 0, 0, 0);
        acc = __builtin_amdgcn_mfma_f32_16x16x32_bf16(afrag[1], b1, acc, 0, 0, 0);

        // epilogue on current tile: C/D row=(q)*4+reg, col=l4
        float m4 = __builtin_inff();
        float t[4];
        #pragma unroll
        for (int reg = 0; reg < 4; ++reg) {
            float dot = acc[reg];
            t[reg] = dot;
            float sq = fmaxf(x2v[reg] + w2c - 2.0f * dot, 1e-12f);
            rowmin[reg] = fminf(rowmin[reg], sq);
            m4 = fminf(m4, sq);
        }
        // col-min: reduce across the 4 quads in-register, single atomic per col
        m4 = fminf(m4, __shfl_xor(m4, 16));
        m4 = fminf(m4, __shfl_xor(m4, 32));
        if (L < 16)
            atomicMin(&s.colmin[ct * 16 + l4], __builtin_bit_cast(unsigned int, m4));

        // 4x4 in-register transpose (lanes 4g..4g+3 x regs) -> float4 row store
        {
            int i = l4 & 3;
            float s0 = (i & 1) ? t[0] : t[1];
            float s1 = (i & 1) ? t[2] : t[3];
            s0 = __shfl_xor(s0, 1); s1 = __shfl_xor(s1, 1);
            if (i & 1) { t[0] = s0; t[2] = s1; } else { t[1] = s0; t[3] = s1; }
            s0 = (i & 2) ? t[0] : t[2];
            s1 = (i & 2) ? t[1] : t[3];
            s0 = __shfl_xor(s0, 2); s1 = __shfl_xor(s1, 2);
            if (i & 2) { t[0] = s0; t[1] = s1; } else { t[2] = s0; t[3] = s1; }
            // lane now holds row q*4+i, cols ct*16 + (l4>>2)*4 .. +3
            float4v st = { t[0], t[1], t[2], t[3] };
            int rowg = rowBase + q * 4 + i;
            *(float4v*)&outp[(size_t)rowg * K_PROT + ct * 16 + (l4 >> 2) * 4] = st;
        }

        b0 = nb0; b1 = nb1; w2c = w2n;
    }

    // ---- phase 3: row-min reduction (min over the 512 cols per row) ----
    #pragma unroll
    for (int m = 1; m <= 8; m <<= 1) {
        #pragma unroll
        for (int reg = 0; reg < 4; ++reg)
            rowmin[reg] = fminf(rowmin[reg], __shfl_xor(rowmin[reg], m));
    }
    float rs = 0.0f;
    if (l4 == 0) {
        #pragma unroll
        for (int reg = 0; reg < 4; ++reg) rs += sqrtf(rowmin[reg]);
    }
    rs += __shfl_xor(rs, 16);
    rs += __shfl_xor(rs, 32);
    if (L == 0) atomicAdd(&s.rowsum, rs);   // wave's 16 rows -> block sum
    __syncthreads();

    // ---- phase 4: flush block results to workspace ----
    atomicMin(&colming[tid],       s.colmin[tid]);
    atomicMin(&colming[tid + 256], s.colmin[tid + 256]);
    if (tid == 0) atomicAdd(rowsumg, s.rowsum);
}

// ---------------- final: scalars ---------------------------------------------
__global__ void final_kernel(const float* __restrict__ recon,
                             const float* __restrict__ kl,
                             const float* __restrict__ mmd,
                             const unsigned int* __restrict__ colmin,
                             const float* __restrict__ rowsum,
                             float* __restrict__ out) {
    __shared__ float wsum[8];
    int tid = threadIdx.x;   // 512 threads
    float v = sqrtf(__builtin_bit_cast(float, colmin[tid]));
    #pragma unroll
    for (int m = 1; m <= 32; m <<= 1) v += __shfl_xor(v, m);
    if ((tid & 63) == 0) wsum[tid >> 6] = v;
    __syncthreads();
    if (tid == 0) {
        float cs = 0.0f;
        #pragma unroll
        for (int i = 0; i < 8; ++i) cs += wsum[i];
        float prot = 0.5f * (rowsum[0] / (float)N_ROWS) + 0.5f * (cs / (float)K_PROT);
        float cvae = recon[0] + 0.5f * kl[0] + mmd[0];
        out[SO + 0] = cvae;
        out[SO + 1] = prot;
    }
}

extern "C" void kernel_launch(void* const* d_in, const int* in_sizes, int n_in,
                              void* d_out, int out_size, void* d_ws, size_t ws_size,
                              hipStream_t stream) {
    const float* x     = (const float*)d_in[0];
    const float* W     = (const float*)d_in[1];
    const float* recon = (const float*)d_in[2];
    const float* kl    = (const float*)d_in[3];
    const float* mmd   = (const float*)d_in[4];
    float* out = (float*)d_out;

    char* ws = (char*)d_ws;
    unsigned int* colmin = (unsigned int*)ws;            // 2048 B
    float*        rowsum = (float*)(ws + 2048);          // 4 B

    prep_kernel<<<1, 512, 0, stream>>>(colmin, rowsum);
    main_kernel<<<N_ROWS / 64, 256, 0, stream>>>(x, W, colmin, rowsum, out);
    final_kernel<<<1, 512, 0, stream>>>(recon, kl, mmd, colmin, rowsum, out);
}

// Round 2
// 387.462 us; speedup vs baseline: 1.1459x; 1.1459x over previous
//
#include <hip/hip_runtime.h>
#include <stdint.h>
#include <stddef.h>

// Problem constants
#define N_ROWS 131072
#define D_DIM  64
#define K_PROT 512
#define ND     (N_ROWS * D_DIM)                       // 8388608 elements per xn copy
#define PO     ((size_t)2 * (size_t)ND)               // proto_out offset (elements)
#define SO     (PO + (size_t)N_ROWS * (size_t)K_PROT) // scalars offset (elements)

#define NBLK   1024                                   // main grid (128 rows/block)

typedef float          float4v  __attribute__((ext_vector_type(4)));
typedef short          short8v  __attribute__((ext_vector_type(8)));
typedef unsigned short ushort4v __attribute__((ext_vector_type(4)));

// fp32 -> bf16 RNE (internal MFMA dtype only; d_out itself is fp32)
__device__ __forceinline__ unsigned short f2bf(float f) {
    unsigned int u = __builtin_bit_cast(unsigned int, f);
    return (unsigned short)((u + 0x7FFFu + ((u >> 16) & 1u)) >> 16);
}

__device__ __forceinline__ float dot4(float4v v) {
    return v.x * v.x + v.y * v.y + v.z * v.z + v.w * v.w;
}

// ---------------- prep: re-init workspace accumulators (runs every launch) ----
__global__ void prep_kernel(unsigned int* __restrict__ colmin,
                            float* __restrict__ rowsum) {
    int k = threadIdx.x;          // 512 threads
    colmin[k] = 0x7F800000u;      // +inf bits
    if (k == 0) *rowsum = 0.0f;
}

// ---------------- main fused kernel ------------------------------------------
// grid 1024 x 512 threads. Block = 8 waves x 16 rows = 128 rows.
// LDS ~69.7 KB -> 2 blocks/CU -> 4 waves/SIMD (was 2). One barrier before MFMA.
// x is loaded directly in A-fragment layout: lane (q,l4) reads row l4,
// d = q*8..q*8+7 and 32+q*8..+7 -> no LDS A-tile, no second barrier.
template<bool BIGWS>
__launch_bounds__(512, 4)
__global__ void main_kernel(const float* __restrict__ x,
                            const float* __restrict__ Wg,
                            unsigned int* __restrict__ colming,
                            float* __restrict__ rowsumg,
                            unsigned int* __restrict__ wsA,
                            float* __restrict__ wsR,
                            float* __restrict__ out) {
    __shared__ unsigned short wlds[K_PROT * D_DIM];  // 65536 B swizzled bf16 W
    __shared__ float w2[K_PROT];                     // 2048 B ||W_k||^2
    __shared__ unsigned int colmin[K_PROT];          // 2048 B block col-min (sq bits)
    __shared__ float rowsum;                         // block sum of sqrt(rowmin)

    const int tid  = threadIdx.x;
    const int wave = tid >> 6;
    const int L    = tid & 63;
    const int q    = L >> 4;   // 16-lane group (quad) 0..3
    const int l4   = L & 15;   // lane within group

    // ---- phase 0: init block LDS accumulators (ordered by the one barrier) ----
    colmin[tid] = 0x7F800000u;
    if (tid == 0) rowsum = 0.0f;

    // ---- phase 1a: stage W -> LDS bf16 swizzled; w2 via 16-lane shuffle ------
    // chunk c of row r stored at c' = c ^ (r&7) => B-frag b128 reads conflict-free.
    {
        const float4v* Wv = (const float4v*)Wg;
        #pragma unroll 4
        for (int i = 0; i < 16; ++i) {
            int idx = tid + 512 * i;        // 0..8191
            float4v v = Wv[idx];
            int r    = idx >> 4;            // row 0..511
            int c    = (idx & 15) >> 1;     // chunk 0..7
            int half = idx & 1;             // low/high 8 B of the chunk
            int cp   = c ^ (r & 7);
            ushort4v p = { f2bf(v.x), f2bf(v.y), f2bf(v.z), f2bf(v.w) };
            *(ushort4v*)&wlds[r * 64 + cp * 8 + half * 4] = p;
            float ss = dot4(v);
            ss += __shfl_xor(ss, 1);
            ss += __shfl_xor(ss, 2);
            ss += __shfl_xor(ss, 4);
            ss += __shfl_xor(ss, 8);        // 16 consecutive lanes hold one W row
            if ((idx & 15) == 0) w2[r] = ss;
        }
    }

    // ---- phase 1b: load x in frag layout, normalize, emit xn, build A-frags --
    const int rowBase = (int)blockIdx.x * 128 + wave * 16;
    const int rowg    = rowBase + l4;            // this lane's x row (= MFMA m)
    const float4v* xr = (const float4v*)(x + (size_t)rowg * D_DIM);

    float4v v0 = xr[2 * q];        // d = q*8   .. q*8+3
    float4v v1 = xr[2 * q + 1];    // d = q*8+4 .. q*8+7
    float4v v2 = xr[2 * q + 8];    // d = 32+q*8 ..
    float4v v3 = xr[2 * q + 9];

    float ss = dot4(v0) + dot4(v1) + dot4(v2) + dot4(v3);
    ss += __shfl_xor(ss, 16);
    ss += __shfl_xor(ss, 32);      // 4 q-lanes of row l4 cover d=0..63
    float scale = 1.0f / fmaxf(sqrtf(ss), 1e-12f);
    v0 *= scale; v1 *= scale; v2 *= scale; v3 *= scale;

    float4v* o0 = (float4v*)(out + (size_t)rowg * D_DIM);
    float4v* o1 = (float4v*)(out + (size_t)ND + (size_t)rowg * D_DIM);
    o0[2 * q] = v0; o0[2 * q + 1] = v1; o0[2 * q + 8] = v2; o0[2 * q + 9] = v3;
    o1[2 * q] = v0; o1[2 * q + 1] = v1; o1[2 * q + 8] = v2; o1[2 * q + 9] = v3;

    // A-frag: lane (q,l4) holds A[m=l4][k=q*8+j (+32)] — exactly what we loaded
    short8v afrag[2];
    afrag[0][0] = (short)f2bf(v0.x); afrag[0][1] = (short)f2bf(v0.y);
    afrag[0][2] = (short)f2bf(v0.z); afrag[0][3] = (short)f2bf(v0.w);
    afrag[0][4] = (short)f2bf(v1.x); afrag[0][5] = (short)f2bf(v1.y);
    afrag[0][6] = (short)f2bf(v1.z); afrag[0][7] = (short)f2bf(v1.w);
    afrag[1][0] = (short)f2bf(v2.x); afrag[1][1] = (short)f2bf(v2.y);
    afrag[1][2] = (short)f2bf(v2.z); afrag[1][3] = (short)f2bf(v2.w);
    afrag[1][4] = (short)f2bf(v3.x); afrag[1][5] = (short)f2bf(v3.y);
    afrag[1][6] = (short)f2bf(v3.z); afrag[1][7] = (short)f2bf(v3.w);

    // x2 of this lane's epilogue rows q*4+reg (C/D layout), via shuffles
    float x2 = ss * scale * scale;
    float4v x2v;
    #pragma unroll
    for (int reg = 0; reg < 4; ++reg)
        x2v[reg] = __shfl(x2, q * 4 + reg);  // lane q*4+reg holds row q*4+reg

    __syncthreads();   // the only pre-MFMA barrier: W/w2/colmin visible

    // ---- phase 2: MFMA over 32 col-tiles, distance-1 pipelined + epilogue ----
    float rowmin[4] = { __builtin_inff(), __builtin_inff(),
                        __builtin_inff(), __builtin_inff() };
    float* outp = out + PO;

    const int cpb0 = (0 * 4 + q) ^ (l4 & 7);   // B-frag swizzled chunk, kh=0
    const int cpb1 = (1 * 4 + q) ^ (l4 & 7);   // kh=1 (rw&7 == l4&7: 16 | ct*16)

    short8v b0 = *(const short8v*)&wlds[l4 * 64 + cpb0 * 8];
    short8v b1 = *(const short8v*)&wlds[l4 * 64 + cpb1 * 8];
    float  w2c = w2[l4];

    #pragma unroll 2
    for (int ct = 0; ct < 32; ++ct) {
        // prefetch ct+1 (wraps harmlessly at ct=31) — hides ds_read latency
        int nrw = (((ct + 1) & 31) * 16) + l4;
        short8v nb0 = *(const short8v*)&wlds[nrw * 64 + cpb0 * 8];
        short8v nb1 = *(const short8v*)&wlds[nrw * 64 + cpb1 * 8];
        float  w2n  = w2[nrw];

        float4v acc = { 0.f, 0.f, 0.f, 0.f };
        acc = __builtin_amdgcn_mfma_f32_16x16x32_bf16(afrag[0], b0, acc, 0, 0, 0);
        acc = __builtin_amdgcn_mfma_f32_16x16x32_bf16(afrag[1], b1, acc, 0, 0, 0);

        // epilogue: C/D row=q*4+reg, col=ct*16+l4
        float m4 = __builtin_inff();
        float t[4];
        #pragma unroll
        for (int reg = 0; reg < 4; ++reg) {
            float dot = acc[reg];
            t[reg] = dot;
            float sq = fmaxf(x2v[reg] + w2c - 2.0f * dot, 1e-12f);
            rowmin[reg] = fminf(rowmin[reg], sq);
            m4 = fminf(m4, sq);
        }
        // col-min: reduce across the 4 quads in-register, one LDS atomic per col
        m4 = fminf(m4, __shfl_xor(m4, 16));
        m4 = fminf(m4, __shfl_xor(m4, 32));
        if (L < 16)
            atomicMin(&colmin[ct * 16 + l4], __builtin_bit_cast(unsigned int, m4));

        // 4x4 in-register transpose (lanes 4g..4g+3 x regs) -> float4 row store
        {
            int i = l4 & 3;
            float s0 = (i & 1) ? t[0] : t[1];
            float s1 = (i & 1) ? t[2] : t[3];
            s0 = __shfl_xor(s0, 1); s1 = __shfl_xor(s1, 1);
            if (i & 1) { t[0] = s0; t[2] = s1; } else { t[1] = s0; t[3] = s1; }
            s0 = (i & 2) ? t[0] : t[2];
            s1 = (i & 2) ? t[1] : t[3];
            s0 = __shfl_xor(s0, 2); s1 = __shfl_xor(s1, 2);
            if (i & 2) { t[0] = s0; t[1] = s1; } else { t[2] = s0; t[3] = s1; }
            // lane now holds row q*4+i, cols ct*16 + (l4>>2)*4 .. +3
            float4v st = { t[0], t[1], t[2], t[3] };
            int rg = rowBase + q * 4 + i;
            *(float4v*)&outp[(size_t)rg * K_PROT + ct * 16 + (l4 >> 2) * 4] = st;
        }

        b0 = nb0; b1 = nb1; w2c = w2n;
    }

    // ---- phase 3: row-min reduction (min over 512 cols per row) --------------
    #pragma unroll
    for (int m = 1; m <= 8; m <<= 1) {
        #pragma unroll
        for (int reg = 0; reg < 4; ++reg)
            rowmin[reg] = fminf(rowmin[reg], __shfl_xor(rowmin[reg], m));
    }
    float rs = 0.0f;
    if (l4 == 0) {
        #pragma unroll
        for (int reg = 0; reg < 4; ++reg) rs += sqrtf(rowmin[reg]);
    }
    rs += __shfl_xor(rs, 16);
    rs += __shfl_xor(rs, 32);
    if (L == 0) atomicAdd(&rowsum, rs);
    __syncthreads();

    // ---- phase 4: flush block results -----------------------------------------
    if (BIGWS) {
        // plain coalesced stores; reduce_kernel folds them (no hot atomics)
        wsA[(size_t)blockIdx.x * K_PROT + tid] = colmin[tid];
        if (tid == 0) wsR[blockIdx.x] = rowsum;
    } else {
        atomicMin(&colming[tid], colmin[tid]);
        if (tid == 0) atomicAdd(rowsumg, rowsum);
    }
}

// ---------------- reduce (BIGWS path): fold 1024 block slices ------------------
__global__ void reduce_kernel(const unsigned int* __restrict__ wsA,
                              const float* __restrict__ wsR,
                              unsigned int* __restrict__ colming,
                              float* __restrict__ rowsumg) {
    int tid = threadIdx.x;        // 512 threads, 64 blocks
    int j   = blockIdx.x;
    unsigned int m = 0x7F800000u;
    #pragma unroll
    for (int i = 0; i < 16; ++i) {
        unsigned int v = wsA[(size_t)(j * 16 + i) * K_PROT + tid]; // coalesced
        m = m < v ? m : v;
    }
    atomicMin(&colming[tid], m);  // 64 x 512 spread atomics (vs 1024 x 512)
    if (j == 0) {
        float v = wsR[tid] + wsR[tid + 512];
        #pragma unroll
        for (int s = 1; s <= 32; s <<= 1) v += __shfl_xor(v, s);
        if ((tid & 63) == 0) atomicAdd(rowsumg, v);   // 8 adds
    }
}

// ---------------- final: scalars ---------------------------------------------
__global__ void final_kernel(const float* __restrict__ recon,
                             const float* __restrict__ kl,
                             const float* __restrict__ mmd,
                             const unsigned int* __restrict__ colmin,
                             const float* __restrict__ rowsum,
                             float* __restrict__ out) {
    __shared__ float wsum[8];
    int tid = threadIdx.x;   // 512 threads
    float v = sqrtf(__builtin_bit_cast(float, colmin[tid]));
    #pragma unroll
    for (int m = 1; m <= 32; m <<= 1) v += __shfl_xor(v, m);
    if ((tid & 63) == 0) wsum[tid >> 6] = v;
    __syncthreads();
    if (tid == 0) {
        float cs = 0.0f;
        #pragma unroll
        for (int i = 0; i < 8; ++i) cs += wsum[i];
        float prot = 0.5f * (rowsum[0] / (float)N_ROWS) + 0.5f * (cs / (float)K_PROT);
        float cvae = recon[0] + 0.5f * kl[0] + mmd[0];
        out[SO + 0] = cvae;
        out[SO + 1] = prot;
    }
}

extern "C" void kernel_launch(void* const* d_in, const int* in_sizes, int n_in,
                              void* d_out, int out_size, void* d_ws, size_t ws_size,
                              hipStream_t stream) {
    const float* x     = (const float*)d_in[0];
    const float* W     = (const float*)d_in[1];
    const float* recon = (const float*)d_in[2];
    const float* kl    = (const float*)d_in[3];
    const float* mmd   = (const float*)d_in[4];
    float* out = (float*)d_out;

    char* ws = (char*)d_ws;
    unsigned int* colmin = (unsigned int*)ws;               // 2048 B
    float*        rowsum = (float*)(ws + 2048);             // 4 B
    unsigned int* wsA    = (unsigned int*)(ws + 4096);      // 1024*512*4 = 2 MB
    float*        wsR    = (float*)(ws + 4096 + (size_t)NBLK * K_PROT * 4);

    const size_t need = 4096 + (size_t)NBLK * K_PROT * 4 + (size_t)NBLK * 4;
    const bool bigws = ws_size >= need;

    prep_kernel<<<1, 512, 0, stream>>>(colmin, rowsum);
    if (bigws) {
        main_kernel<true><<<NBLK, 512, 0, stream>>>(x, W, colmin, rowsum, wsA, wsR, out);
        reduce_kernel<<<64, 512, 0, stream>>>(wsA, wsR, colmin, rowsum);
    } else {
        main_kernel<false><<<NBLK, 512, 0, stream>>>(x, W, colmin, rowsum, wsA, wsR, out);
    }
    final_kernel<<<1, 512, 0, stream>>>(recon, kl, mmd, colmin, rowsum, out);
}

// Round 3
// 386.687 us; speedup vs baseline: 1.1482x; 1.0020x over previous
//
#include <hip/hip_runtime.h>
#include <stdint.h>
#include <stddef.h>

// Problem constants
#define N_ROWS 131072
#define D_DIM  64
#define K_PROT 512
#define ND     (N_ROWS * D_DIM)                       // 8388608 elements per xn copy
#define PO     ((size_t)2 * (size_t)ND)               // proto_out offset (elements)
#define SO     (PO + (size_t)N_ROWS * (size_t)K_PROT) // scalars offset (elements)

#define NBLK   1024                                   // main grid (128 rows/block)

typedef float          float4v  __attribute__((ext_vector_type(4)));
typedef short          short8v  __attribute__((ext_vector_type(8)));
typedef unsigned short ushort4v __attribute__((ext_vector_type(4)));

// fp32 -> bf16 RNE (internal MFMA dtype only; d_out itself is fp32)
__device__ __forceinline__ unsigned short f2bf(float f) {
    unsigned int u = __builtin_bit_cast(unsigned int, f);
    return (unsigned short)((u + 0x7FFFu + ((u >> 16) & 1u)) >> 16);
}

__device__ __forceinline__ float dot4(float4v v) {
    return v.x * v.x + v.y * v.y + v.z * v.z + v.w * v.w;
}

// ---------------- prep: re-init workspace accumulators (runs every launch) ----
__global__ void prep_kernel(unsigned int* __restrict__ colmin,
                            float* __restrict__ rowsum) {
    int k = threadIdx.x;          // 512 threads
    colmin[k] = 0x7F800000u;      // +inf bits
    if (k == 0) *rowsum = 0.0f;
}

// ---------------- main fused kernel ------------------------------------------
// grid 1024 x 512 threads. Block = 8 waves x 16 rows = 128 rows.
// W is staged in TWO 256-row halves (32 KB each) -> LDS ~36.9 KB
// -> 3 blocks/CU (6 waves/SIMD) instead of 2 (4 waves/SIMD).
// x loaded directly in A-fragment layout (no LDS A-tile).
template<bool BIGWS>
__launch_bounds__(512, 6)
__global__ void main_kernel(const float* __restrict__ x,
                            const float* __restrict__ Wg,
                            unsigned int* __restrict__ colming,
                            float* __restrict__ rowsumg,
                            unsigned int* __restrict__ wsA,
                            float* __restrict__ wsR,
                            float* __restrict__ out) {
    __shared__ unsigned short wlds[256 * D_DIM];     // 32768 B swizzled bf16 W half
    __shared__ float w2[K_PROT];                     // 2048 B ||W_k||^2
    __shared__ unsigned int colmin[K_PROT];          // 2048 B block col-min (sq bits)
    __shared__ float rowsum;                         // block sum of sqrt(rowmin)

    const int tid  = threadIdx.x;
    const int wave = tid >> 6;
    const int L    = tid & 63;
    const int q    = L >> 4;   // 16-lane group (quad) 0..3
    const int l4   = L & 15;   // lane within group

    // ---- phase 0: init block LDS accumulators (ordered by first barrier) -----
    colmin[tid] = 0x7F800000u;
    if (tid == 0) rowsum = 0.0f;

    // ---- issue x loads first: HBM latency hides under W staging --------------
    const int rowBase = (int)blockIdx.x * 128 + wave * 16;
    const int rowg    = rowBase + l4;            // this lane's x row (= MFMA m)
    const float4v* xr = (const float4v*)(x + (size_t)rowg * D_DIM);
    float4v v0 = xr[2 * q];        // d = q*8   .. q*8+3
    float4v v1 = xr[2 * q + 1];    // d = q*8+4 .. q*8+7
    float4v v2 = xr[2 * q + 8];    // d = 32+q*8 ..
    float4v v3 = xr[2 * q + 9];

    // ---- phase 1a: stage W half 0 -> LDS bf16 swizzled; w2 via shuffles ------
    // chunk c of row r stored at c' = c ^ (r&7) => B-frag b128 reads conflict-free.
    {
        const float4v* Wv = (const float4v*)Wg;   // half 0: rows 0..255
        #pragma unroll 4
        for (int i = 0; i < 8; ++i) {
            int idx = tid + 512 * i;        // 0..4095
            float4v v = Wv[idx];
            int r    = idx >> 4;            // row 0..255
            int c    = (idx & 15) >> 1;     // chunk 0..7
            int h16  = idx & 1;             // low/high 8 B of the chunk
            int cp   = c ^ (r & 7);
            ushort4v p = { f2bf(v.x), f2bf(v.y), f2bf(v.z), f2bf(v.w) };
            *(ushort4v*)&wlds[r * 64 + cp * 8 + h16 * 4] = p;
            float ss = dot4(v);
            ss += __shfl_xor(ss, 1);
            ss += __shfl_xor(ss, 2);
            ss += __shfl_xor(ss, 4);
            ss += __shfl_xor(ss, 8);        // 16 consecutive lanes hold one W row
            if ((idx & 15) == 0) w2[r] = ss;
        }
    }

    // ---- phase 1b: normalize x, emit xn, build A-frags (no LDS, no barrier) --
    float ss = dot4(v0) + dot4(v1) + dot4(v2) + dot4(v3);
    ss += __shfl_xor(ss, 16);
    ss += __shfl_xor(ss, 32);      // 4 q-lanes of row l4 cover d=0..63
    float scale = 1.0f / fmaxf(sqrtf(ss), 1e-12f);
    v0 *= scale; v1 *= scale; v2 *= scale; v3 *= scale;

    float4v* o0 = (float4v*)(out + (size_t)rowg * D_DIM);
    float4v* o1 = (float4v*)(out + (size_t)ND + (size_t)rowg * D_DIM);
    o0[2 * q] = v0; o0[2 * q + 1] = v1; o0[2 * q + 8] = v2; o0[2 * q + 9] = v3;
    o1[2 * q] = v0; o1[2 * q + 1] = v1; o1[2 * q + 8] = v2; o1[2 * q + 9] = v3;

    // A-frag: lane (q,l4) holds A[m=l4][k=q*8+j (+32)] — exactly what we loaded
    short8v afrag[2];
    afrag[0][0] = (short)f2bf(v0.x); afrag[0][1] = (short)f2bf(v0.y);
    afrag[0][2] = (short)f2bf(v0.z); afrag[0][3] = (short)f2bf(v0.w);
    afrag[0][4] = (short)f2bf(v1.x); afrag[0][5] = (short)f2bf(v1.y);
    afrag[0][6] = (short)f2bf(v1.z); afrag[0][7] = (short)f2bf(v1.w);
    afrag[1][0] = (short)f2bf(v2.x); afrag[1][1] = (short)f2bf(v2.y);
    afrag[1][2] = (short)f2bf(v2.z); afrag[1][3] = (short)f2bf(v2.w);
    afrag[1][4] = (short)f2bf(v3.x); afrag[1][5] = (short)f2bf(v3.y);
    afrag[1][6] = (short)f2bf(v3.z); afrag[1][7] = (short)f2bf(v3.w);

    // x2 of this lane's epilogue rows q*4+reg (C/D layout), via shuffles
    float x2 = ss * scale * scale;
    float4v x2v;
    #pragma unroll
    for (int reg = 0; reg < 4; ++reg)
        x2v[reg] = __shfl(x2, q * 4 + reg);  // lane q*4+reg holds row q*4+reg

    float rowmin[4] = { __builtin_inff(), __builtin_inff(),
                        __builtin_inff(), __builtin_inff() };
    float* outp = out + PO;
    const int cpb0 = (0 * 4 + q) ^ (l4 & 7);   // B-frag swizzled chunk, kh=0
    const int cpb1 = (1 * 4 + q) ^ (l4 & 7);   // kh=1 (lr&7 == l4&7: 16 | ct*16)

    // ---- phase 2: two W-halves, each: [stage] -> sync -> 16 col-tiles --------
    #pragma unroll
    for (int h = 0; h < 2; ++h) {
        if (h == 1) {
            __syncthreads();   // everyone done reading wlds half 0
            const float4v* Wv = (const float4v*)Wg + 4096; // rows 256..511
            #pragma unroll 4
            for (int i = 0; i < 8; ++i) {
                int idx = tid + 512 * i;
                float4v v = Wv[idx];
                int r    = idx >> 4;
                int c    = (idx & 15) >> 1;
                int h16  = idx & 1;
                int cp   = c ^ (r & 7);
                ushort4v p = { f2bf(v.x), f2bf(v.y), f2bf(v.z), f2bf(v.w) };
                *(ushort4v*)&wlds[r * 64 + cp * 8 + h16 * 4] = p;
                float ws_ = dot4(v);
                ws_ += __shfl_xor(ws_, 1);
                ws_ += __shfl_xor(ws_, 2);
                ws_ += __shfl_xor(ws_, 4);
                ws_ += __shfl_xor(ws_, 8);
                if ((idx & 15) == 0) w2[256 + r] = ws_;
            }
        }
        __syncthreads();       // staged half + w2 visible (h=0: also colmin init)

        // prologue: prefetch local tile 0
        short8v b0 = *(const short8v*)&wlds[l4 * 64 + cpb0 * 8];
        short8v b1 = *(const short8v*)&wlds[l4 * 64 + cpb1 * 8];
        float  w2c = w2[h * 256 + l4];

        #pragma unroll 2
        for (int ct = 0; ct < 16; ++ct) {
            // prefetch ct+1 (wraps harmlessly at ct=15)
            int nlr = (((ct + 1) & 15) * 16) + l4;
            short8v nb0 = *(const short8v*)&wlds[nlr * 64 + cpb0 * 8];
            short8v nb1 = *(const short8v*)&wlds[nlr * 64 + cpb1 * 8];
            float  w2n  = w2[h * 256 + nlr];

            float4v acc = { 0.f, 0.f, 0.f, 0.f };
            acc = __builtin_amdgcn_mfma_f32_16x16x32_bf16(afrag[0], b0, acc, 0, 0, 0);
            acc = __builtin_amdgcn_mfma_f32_16x16x32_bf16(afrag[1], b1, acc, 0, 0, 0);

            // epilogue: C/D row=q*4+reg, col = h*256 + ct*16 + l4
            const int colg = h * 256 + ct * 16 + l4;
            float m4 = __builtin_inff();
            float t[4];
            #pragma unroll
            for (int reg = 0; reg < 4; ++reg) {
                float dot = acc[reg];
                t[reg] = dot;
                float sq = fmaxf(x2v[reg] + w2c - 2.0f * dot, 1e-12f);
                rowmin[reg] = fminf(rowmin[reg], sq);
                m4 = fminf(m4, sq);
            }
            // col-min: all 4 quads atomic the same col (4-way ~1.6x, cheaper
            // than 2 cross-quad shuffles + quarter-wave atomic)
            atomicMin(&colmin[colg], __builtin_bit_cast(unsigned int, m4));

            // 4x4 in-register transpose (lanes 4g..4g+3 x regs) -> float4 store
            {
                int i = l4 & 3;
                float s0 = (i & 1) ? t[0] : t[1];
                float s1 = (i & 1) ? t[2] : t[3];
                s0 = __shfl_xor(s0, 1); s1 = __shfl_xor(s1, 1);
                if (i & 1) { t[0] = s0; t[2] = s1; } else { t[1] = s0; t[3] = s1; }
                s0 = (i & 2) ? t[0] : t[2];
                s1 = (i & 2) ? t[1] : t[3];
                s0 = __shfl_xor(s0, 2); s1 = __shfl_xor(s1, 2);
                if (i & 2) { t[0] = s0; t[1] = s1; } else { t[2] = s0; t[3] = s1; }
                // lane holds row q*4+i, cols h*256 + ct*16 + (l4>>2)*4 .. +3
                float4v st = { t[0], t[1], t[2], t[3] };
                int rg = rowBase + q * 4 + i;
                *(float4v*)&outp[(size_t)rg * K_PROT + h * 256 + ct * 16
                                 + (l4 >> 2) * 4] = st;
            }

            b0 = nb0; b1 = nb1; w2c = w2n;
        }
    }

    // ---- phase 3: row-min reduction (min over 512 cols per row) --------------
    #pragma unroll
    for (int m = 1; m <= 8; m <<= 1) {
        #pragma unroll
        for (int reg = 0; reg < 4; ++reg)
            rowmin[reg] = fminf(rowmin[reg], __shfl_xor(rowmin[reg], m));
    }
    float rs = 0.0f;
    if (l4 == 0) {
        #pragma unroll
        for (int reg = 0; reg < 4; ++reg) rs += sqrtf(rowmin[reg]);
    }
    rs += __shfl_xor(rs, 16);
    rs += __shfl_xor(rs, 32);
    if (L == 0) atomicAdd(&rowsum, rs);
    __syncthreads();

    // ---- phase 4: flush block results -----------------------------------------
    if (BIGWS) {
        // plain coalesced stores; reduce_kernel folds them (no hot atomics)
        wsA[(size_t)blockIdx.x * K_PROT + tid] = colmin[tid];
        if (tid == 0) wsR[blockIdx.x] = rowsum;
    } else {
        atomicMin(&colming[tid], colmin[tid]);
        if (tid == 0) atomicAdd(rowsumg, rowsum);
    }
}

// ---------------- reduce (BIGWS path): fold 1024 block slices ------------------
__global__ void reduce_kernel(const unsigned int* __restrict__ wsA,
                              const float* __restrict__ wsR,
                              unsigned int* __restrict__ colming,
                              float* __restrict__ rowsumg) {
    int tid = threadIdx.x;        // 512 threads, 64 blocks
    int j   = blockIdx.x;
    unsigned int m = 0x7F800000u;
    #pragma unroll
    for (int i = 0; i < 16; ++i) {
        unsigned int v = wsA[(size_t)(j * 16 + i) * K_PROT + tid]; // coalesced
        m = m < v ? m : v;
    }
    atomicMin(&colming[tid], m);  // 64 x 512 spread atomics
    if (j == 0) {
        float v = wsR[tid] + wsR[tid + 512];
        #pragma unroll
        for (int s = 1; s <= 32; s <<= 1) v += __shfl_xor(v, s);
        if ((tid & 63) == 0) atomicAdd(rowsumg, v);   // 8 adds
    }
}

// ---------------- final: scalars ---------------------------------------------
__global__ void final_kernel(const float* __restrict__ recon,
                             const float* __restrict__ kl,
                             const float* __restrict__ mmd,
                             const unsigned int* __restrict__ colmin,
                             const float* __restrict__ rowsum,
                             float* __restrict__ out) {
    __shared__ float wsum[8];
    int tid = threadIdx.x;   // 512 threads
    float v = sqrtf(__builtin_bit_cast(float, colmin[tid]));
    #pragma unroll
    for (int m = 1; m <= 32; m <<= 1) v += __shfl_xor(v, m);
    if ((tid & 63) == 0) wsum[tid >> 6] = v;
    __syncthreads();
    if (tid == 0) {
        float cs = 0.0f;
        #pragma unroll
        for (int i = 0; i < 8; ++i) cs += wsum[i];
        float prot = 0.5f * (rowsum[0] / (float)N_ROWS) + 0.5f * (cs / (float)K_PROT);
        float cvae = recon[0] + 0.5f * kl[0] + mmd[0];
        out[SO + 0] = cvae;
        out[SO + 1] = prot;
    }
}

extern "C" void kernel_launch(void* const* d_in, const int* in_sizes, int n_in,
                              void* d_out, int out_size, void* d_ws, size_t ws_size,
                              hipStream_t stream) {
    const float* x     = (const float*)d_in[0];
    const float* W     = (const float*)d_in[1];
    const float* recon = (const float*)d_in[2];
    const float* kl    = (const float*)d_in[3];
    const float* mmd   = (const float*)d_in[4];
    float* out = (float*)d_out;

    char* ws = (char*)d_ws;
    unsigned int* colmin = (unsigned int*)ws;               // 2048 B
    float*        rowsum = (float*)(ws + 2048);             // 4 B
    unsigned int* wsA    = (unsigned int*)(ws + 4096);      // 1024*512*4 = 2 MB
    float*        wsR    = (float*)(ws + 4096 + (size_t)NBLK * K_PROT * 4);

    const size_t need = 4096 + (size_t)NBLK * K_PROT * 4 + (size_t)NBLK * 4;
    const bool bigws = ws_size >= need;

    prep_kernel<<<1, 512, 0, stream>>>(colmin, rowsum);
    if (bigws) {
        main_kernel<true><<<NBLK, 512, 0, stream>>>(x, W, colmin, rowsum, wsA, wsR, out);
        reduce_kernel<<<64, 512, 0, stream>>>(wsA, wsR, colmin, rowsum);
    } else {
        main_kernel<false><<<NBLK, 512, 0, stream>>>(x, W, colmin, rowsum, wsA, wsR, out);
    }
    final_kernel<<<1, 512, 0, stream>>>(recon, kl, mmd, colmin, rowsum, out);
}